// Round 11
// baseline (261.444 us; speedup 1.0000x reference)
//
#include <hip/hip_runtime.h>

// ---- workspace layout (short elements) ----
// K pack  [h][7168][64] bf16                 @ 0
// V^T s0  [h][64][7168] bf16                 @ VB0
// V^T s1  [h][64][3584]                      @ VB1
// V^T s2  [h][64][1792]                      @ VB2
#define VB0 3670016L
#define VB1 7340032L
#define VB2 9175040L
// partial region (same byte footprint as the proven fp32 [512] layout):
// PO: [1024][128][64] fp16   @ byte offset 4*PO_OFF
// PL: [1024][128]     fp16   following
#define PO_OFF 5046272L

typedef short bvec8 __attribute__((ext_vector_type(8)));
typedef float fvec16 __attribute__((ext_vector_type(16)));
typedef _Float16 hvec4 __attribute__((ext_vector_type(4)));
typedef _Float16 hvec8 __attribute__((ext_vector_type(8)));

#if defined(__has_builtin)
#if __has_builtin(__builtin_amdgcn_cvt_pk_bf16_f32)
#define HAVE_CVTPK 1
#endif
#if __has_builtin(__builtin_amdgcn_permlane32_swap)
#define HAVE_PLSWAP 1
#endif
#endif

static __device__ __forceinline__ unsigned pk2(float a, float b) {
#ifdef HAVE_CVTPK
  auto r = __builtin_amdgcn_cvt_pk_bf16_f32(a, b);  // single v_cvt_pk_bf16_f32
  unsigned u; __builtin_memcpy(&u, &r, 4);
  return u;
#else
  unsigned ua = (__float_as_uint(a) + 0x8000u) >> 16;
  unsigned ub = (__float_as_uint(b) + 0x8000u) & 0xffff0000u;
  return ua | ub;
#endif
}

// ---------------- fused packs: K bf16 copy + V^T bf16 transpose ----------------
__global__ __launch_bounds__(256) void pack_all(const float* __restrict__ k,
                                                const float* __restrict__ v,
                                                short* __restrict__ W) {
  __shared__ float tl[64][65];
  int b = blockIdx.x, t = threadIdx.x;
  if (b < 896) {  // K pack: [h][7168][64], 16 contiguous elements/thread
    int h = b / 112, tile = b % 112, i0 = tile * 64;
    int r = t >> 2, c = t & 3;
    const float* src = k + ((long)(i0 + r) * 8 + h) * 64 + c * 16;
    short* dst = W + ((long)h * 7168 + i0 + r) * 64 + c * 16;
    union { unsigned u[8]; bvec8 v[2]; } tw;
#pragma unroll
    for (int q4 = 0; q4 < 4; q4++) {
      float4 x = *(const float4*)(src + q4 * 4);
      tw.u[q4 * 2 + 0] = pk2(x.x, x.y);
      tw.u[q4 * 2 + 1] = pk2(x.z, x.w);
    }
    *(bvec8*)dst = tw.v[0];
    *(bvec8*)(dst + 8) = tw.v[1];
  } else {        // V^T pack
    int b2 = b - 896;
    int h, tile, dil, L; long base;
    if (b2 < 896)       { L = 7168; dil = 1; h = b2 / 112; tile = b2 % 112; base = VB0; }
    else if (b2 < 1344) { int bb = b2 - 896;  L = 3584; dil = 2; h = bb / 56; tile = bb % 56; base = VB1; }
    else                { int bb = b2 - 1344; L = 1792; dil = 4; h = bb / 28; tile = bb % 28; base = VB2; }
    int i0 = tile * 64;
    int row = t >> 2, c = t & 3;
    const float* src = v + ((long)(i0 + row) * dil * 8 + h) * 64;
#pragma unroll
    for (int cc = 0; cc < 4; cc++) {
      int d0 = c * 16 + cc * 4;
      float4 x = *(const float4*)(src + d0);
      tl[row][d0 + 0] = x.x; tl[row][d0 + 1] = x.y;
      tl[row][d0 + 2] = x.z; tl[row][d0 + 3] = x.w;
    }
    __syncthreads();
    int d = t >> 2, part = t & 3;
    union { unsigned u[8]; bvec8 v[2]; } tw;
#pragma unroll
    for (int u2 = 0; u2 < 8; u2++)
      tw.u[u2] = pk2(tl[part * 16 + 2 * u2][d], tl[part * 16 + 2 * u2 + 1][d]);
    short* dst = W + base + ((long)h * 64 + d) * L + i0 + part * 16;
    *(bvec8*)dst = tw.v[0];
    *(bvec8*)(dst + 8) = tw.v[1];
  }
}

// cross-half P exchange
#ifdef HAVE_PLSWAP
#define PEXCH(fu, da0, da1, db0, db1)                                              \
  do {                                                                             \
    auto rr0 = __builtin_amdgcn_permlane32_swap((int)(da0), (int)(db0), false, false); \
    auto rr1 = __builtin_amdgcn_permlane32_swap((int)(da1), (int)(db1), false, false); \
    __builtin_memcpy(&fu.u4[0], &rr0, 4);                                          \
    __builtin_memcpy(&fu.u4[2], (const char*)&rr0 + 4, 4);                         \
    __builtin_memcpy(&fu.u4[1], &rr1, 4);                                          \
    __builtin_memcpy(&fu.u4[3], (const char*)&rr1 + 4, 4);                         \
  } while (0)
#else
#define PEXCH(fu, da0, da1, db0, db1)                                              \
  do {                                                                             \
    unsigned s0 = hb ? (da0) : (db0), s1 = hb ? (da1) : (db1);                     \
    unsigned x0 = __shfl_xor(s0, 32), x1 = __shfl_xor(s1, 32);                     \
    fu.u4[0] = hb ? x0 : (da0);  fu.u4[1] = hb ? x1 : (da1);                       \
    fu.u4[2] = hb ? (db0) : x0;  fu.u4[3] = hb ? (db1) : x1;                       \
  } while (0)
#endif

// one softmax slot from a single-key-half Sa: exp2 on 8 scores + l-accumulate +
// P pack/exchange + 2 PV MFMAs (V0 = d-half 0 fragment, V1 = d-half 1)
#define SOFTMAX_PV_H(SA, V0, V1, SP)                                               \
  do {                                                                             \
    const int r0_ = (SP) * 8;                                                      \
    float p[8];                                                                    \
    _Pragma("unroll") for (int u = 0; u < 8; u++)                                  \
        p[u] = __builtin_amdgcn_exp2f(SA[r0_ + u]);                                \
    lacc += ((p[0] + p[1]) + (p[2] + p[3])) + ((p[4] + p[5]) + (p[6] + p[7]));     \
    unsigned da0 = pk2(p[0], p[1]), da1 = pk2(p[2], p[3]);                         \
    unsigned db0 = pk2(p[4], p[5]), db1 = pk2(p[6], p[7]);                         \
    union { unsigned u4[4]; bvec8 v; } fu;                                         \
    PEXCH(fu, da0, da1, db0, db1);                                                 \
    __builtin_amdgcn_s_setprio(1);                                                 \
    Oa[0] = __builtin_amdgcn_mfma_f32_32x32x16_bf16((V0), fu.v, Oa[0], 0, 0, 0);   \
    Oa[1] = __builtin_amdgcn_mfma_f32_32x32x16_bf16((V1), fu.v, Oa[1], 0, 0, 0);   \
    __builtin_amdgcn_s_setprio(0);                                                 \
  } while (0)

// --------------------- main flash attention (S^T form) ---------------------
// R19: ZERO LDS, ZERO BARRIERS. R10-R18 showed attn pinned at 67-72us across
// six schedule/grid variants — the un-ablated invariant was barrier-coupled
// LDS staging (4 waves lock-step, LDS-pipe bursts, slowest-wave pacing).
// Here each wave loads its 16 fragments/tile DIRECTLY from the packed W:
//   K frag (half,ks):  kp(tile) + half*32*dil64 + ln*dil64 + hb*8 + ks*16
//   V frag (s,dh):     vp(tile) + (dh*32+ln)*L  + hb*8 + s*16
// (global chunk = 2ks+hb: the LDS XOR-swizzle cancels against the staging
// swizzle, verified algebraically against the R17 layout.)
// Same-CU waves share tile lines via L1 (TCC FETCH unchanged); prefetch is
// staggered at dead points (K-half after its QK ~1500cyc slack, V-pair after
// its PV ~900cyc) so single-buffered regs suffice (~150 live).
// Waves fully independent -> 12 free-running waves/CU instead of 3 lock-stepped
// blocks. Tail prefetch (tile NT) lands inside the workspace (layout-verified).
// Grid/partials = R17 (measured best): 1280 blocks, seg2-first, fp16 PO/PL.
__global__ __launch_bounds__(256, 3) void attn_kern(const float* __restrict__ q,
                                                    const short* __restrict__ W,
                                                    float* __restrict__ out,
                                                    _Float16* __restrict__ POh,
                                                    _Float16* __restrict__ PLh) {
  int b = blockIdx.x;
  int h, q0, dil, kt0, L, NT, pb; long vbo;
  if (b < 256) {        // seg2: long blocks first (28 tiles, direct out)
    h = b & 7; int qt = b >> 3;
    q0 = 3072 + qt * 128; dil = 4; L = 1792; vbo = VB2; kt0 = 0; NT = 28; pb = -1;
  } else if (b < 768) { // seg0: 8 splits x 14 tiles
    int i = b - 256; int sp = i & 7; h = (i >> 3) & 7; int qt = i >> 6;
    q0 = qt * 128; dil = 1; L = 7168; vbo = VB0; kt0 = sp * 14; NT = 14; pb = i;
  } else {              // seg1: 4 splits x 14 tiles
    int i = b - 768; int sp = i & 3; h = (i >> 2) & 7; int qt = i >> 5;
    q0 = 1024 + qt * 128; dil = 2; L = 3584; vbo = VB1; kt0 = sp * 14; NT = 14; pb = 512 + i;
  }
  const short* kb = W + (long)h * 7168 * 64;
  const short* vt = W + vbo + (long)h * 64 * L;
  const int dil64 = dil * 64;

  int t = threadIdx.x, lane = t & 63, w = t >> 6;
  int ln = lane & 31, hb = lane >> 5;

  // Q as B-operand (n = q-row = ln, k-els d = 16*ks + 8*hb + j), scale folds 1/8 * log2(e)
  bvec8 qb[4];
  {
    const float* qp = q + ((long)(q0 + w * 32 + ln) * 8 + h) * 64 + 8 * hb;
    const float qs = 0.125f * 1.44269504088896f;
#pragma unroll
    for (int ks = 0; ks < 4; ks++) {
      union { unsigned u[4]; bvec8 v; } qu;
#pragma unroll
      for (int jj = 0; jj < 4; jj++)
        qu.u[jj] = pk2(qs * qp[ks * 16 + 2 * jj], qs * qp[ks * 16 + 2 * jj + 1]);
      qb[ks] = qu.v;
    }
  }

  // per-tile uniform bases (SGPR) + per-lane offsets (VGPR)
  const long kstep = 64L * dil64;                 // shorts per K-tile advance
  const short* kp0 = kb + (long)kt0 * kstep;      // key-half 0 base, tile 0
  const short* kp1 = kp0 + 32 * dil64;            // key-half 1 base
  const short* vp  = vt + kt0 * 64;               // V tile base
  const int lk  = ln * dil64 + hb * 8;            // K lane offset (shorts)
  const int lv0 = ln * L + hb * 8;                // V lane offset, d-half 0
  const int lv1 = (32 + ln) * L + hb * 8;         // V lane offset, d-half 1

  // fragment registers: kf[half*4+ks], vf[s*2+dh] (s = global key-slot 0..3)
  bvec8 kf[8], vf[8];
#pragma unroll
  for (int ks = 0; ks < 4; ks++) {
    kf[ks]     = *(const bvec8*)(kp0 + lk + ks * 16);
    kf[4 + ks] = *(const bvec8*)(kp1 + lk + ks * 16);
  }
#pragma unroll
  for (int s = 0; s < 4; s++) {
    vf[s * 2 + 0] = *(const bvec8*)(vp + lv0 + s * 16);
    vf[s * 2 + 1] = *(const bvec8*)(vp + lv1 + s * 16);
  }
  kp0 += kstep; kp1 += kstep; vp += 64;   // point at tile 1

  fvec16 Oa[2];
  float lacc = 0.f;
#pragma unroll
  for (int i = 0; i < 16; i++) { Oa[0][i] = 0.f; Oa[1][i] = 0.f; }

  for (int it = 0; it < NT; it++) {
#pragma unroll
    for (int half = 0; half < 2; half++) {
      const short* kp = half ? kp1 : kp0;
      // S^T(half) = K_half * Q^T from registers
      fvec16 Sa;
#pragma unroll
      for (int i = 0; i < 16; i++) Sa[i] = 0.f;
      __builtin_amdgcn_s_setprio(1);
#pragma unroll
      for (int ks = 0; ks < 4; ks++)
        Sa = __builtin_amdgcn_mfma_f32_32x32x16_bf16(kf[half * 4 + ks], qb[ks], Sa, 0, 0, 0);
      __builtin_amdgcn_s_setprio(0);

      // prefetch next tile's K fragments for this half (dead after QK above);
      // in flight across this half's softmax+PV and beyond (~1500 cyc slack)
#pragma unroll
      for (int ks = 0; ks < 4; ks++)
        kf[half * 4 + ks] = *(const bvec8*)(kp + lk + ks * 16);

      SOFTMAX_PV_H(Sa, vf[half * 4 + 0], vf[half * 4 + 1], 0);
      SOFTMAX_PV_H(Sa, vf[half * 4 + 2], vf[half * 4 + 3], 1);

      // prefetch next tile's V fragments for this half's slots (just consumed);
      // in flight across the other half + next QK (~900 cyc slack)
#pragma unroll
      for (int s2 = 0; s2 < 2; s2++) {
        int s = half * 2 + s2;
        vf[half * 4 + s2 * 2 + 0] = *(const bvec8*)(vp + lv0 + s * 16);
        vf[half * 4 + s2 * 2 + 1] = *(const bvec8*)(vp + lv1 + s * 16);
      }
    }
    kp0 += kstep; kp1 += kstep; vp += 64;
    // (tail prefetch at it = NT-1 reads tile NT: stays inside d_ws, unused)
  }

  // epilogue: O^T C-layout: qrow = ln, d = 32*mb2 + 8*r2 + 4*hb + r3
  float lf = lacc + __shfl_xor(lacc, 32);
  int wl = w * 32 + ln;
  if (pb >= 0) {
    _Float16* po = POh + ((long)pb * 128 + wl) * 64;
#pragma unroll
    for (int mb2 = 0; mb2 < 2; mb2++)
#pragma unroll
      for (int r2 = 0; r2 < 4; r2++) {
        hvec4 x = { (_Float16)Oa[mb2][r2 * 4 + 0], (_Float16)Oa[mb2][r2 * 4 + 1],
                    (_Float16)Oa[mb2][r2 * 4 + 2], (_Float16)Oa[mb2][r2 * 4 + 3] };
        *(hvec4*)(po + mb2 * 32 + r2 * 8 + hb * 4) = x;
      }
    if (hb == 0) PLh[(long)pb * 128 + wl] = (_Float16)lf;
  } else {
    float inv = 1.f / lf;
    float* op = out + ((long)(q0 + wl) * 8 + h) * 64;
#pragma unroll
    for (int mb2 = 0; mb2 < 2; mb2++)
#pragma unroll
      for (int r2 = 0; r2 < 4; r2++) {
        float4 x = { Oa[mb2][r2 * 4 + 0] * inv, Oa[mb2][r2 * 4 + 1] * inv,
                     Oa[mb2][r2 * 4 + 2] * inv, Oa[mb2][r2 * 4 + 3] * inv };
        *(float4*)(op + mb2 * 32 + r2 * 8 + hb * 4) = x;
      }
  }
}

// --------------- combine partials (seg0: 8 splits, seg1: 4 splits) ---------------
__global__ __launch_bounds__(256) void combine_kern(const _Float16* __restrict__ POh,
                                                    const _Float16* __restrict__ PLh,
                                                    float* __restrict__ out) {
  int g = blockIdx.x, t = threadIdx.x;
  int base, nsp, q0, h;
  if (g < 64) { int qt = g >> 3; h = g & 7; base = qt * 64 + h * 8; nsp = 8; q0 = qt * 128; }
  else { int gi = g - 64; int qt = gi >> 3; h = gi & 7; base = 512 + qt * 32 + h * 4; nsp = 4; q0 = 1024 + qt * 128; }
  int r = t >> 1, ch = (t & 1) * 32;
  float lt = 0.f;
  for (int sp = 0; sp < nsp; sp++) lt += (float)PLh[(long)(base + sp) * 128 + r];
  float inv = 1.f / lt;
  float acc[32];
#pragma unroll
  for (int j = 0; j < 32; j++) acc[j] = 0.f;
  for (int sp = 0; sp < nsp; sp++) {
    const hvec8* pb8 = (const hvec8*)(POh + ((long)(base + sp) * 128 + r) * 64 + ch);
#pragma unroll
    for (int j = 0; j < 4; j++) {
      hvec8 x = pb8[j];
#pragma unroll
      for (int kk = 0; kk < 8; kk++) acc[j * 8 + kk] += (float)x[kk];
    }
  }
  float4* op = (float4*)(out + ((long)(q0 + r) * 8 + h) * 64 + ch);
#pragma unroll
  for (int j = 0; j < 8; j++) {
    float4 x = { acc[j * 4 + 0] * inv, acc[j * 4 + 1] * inv,
                 acc[j * 4 + 2] * inv, acc[j * 4 + 3] * inv };
    op[j] = x;
  }
}

extern "C" void kernel_launch(void* const* d_in, const int* in_sizes, int n_in,
                              void* d_out, int out_size, void* d_ws, size_t ws_size,
                              hipStream_t stream) {
  const float* q = (const float*)d_in[0];
  const float* k = (const float*)d_in[1];
  const float* v = (const float*)d_in[2];
  float* out = (float*)d_out;
  short* W = (short*)d_ws;                 // bf16 packs (unchanged)
  _Float16* POh = (_Float16*)((float*)d_ws + PO_OFF);   // [1024][128][64] fp16
  _Float16* PLh = POh + 1024L * 128 * 64;               // [1024][128] fp16

  pack_all<<<2464, 256, 0, stream>>>(k, v, W);
  attn_kern<<<1280, 256, 0, stream>>>(q, W, out, POh, PLh);
  combine_kern<<<192, 256, 0, stream>>>(POh, PLh, out);
}

// Round 12
// 157.246 us; speedup vs baseline: 1.6626x; 1.6626x over previous
//
#include <hip/hip_runtime.h>

// ---- workspace layout (short elements) ----
// K pack  [h][7168][64] bf16                 @ 0
// V^T s0  [h][64][7168] bf16                 @ VB0
// V^T s1  [h][64][3584]                      @ VB1
// V^T s2  [h][64][1792]                      @ VB2
#define VB0 3670016L
#define VB1 7340032L
#define VB2 9175040L
// partial region (same byte footprint as the proven fp32 [512] layout):
// PO: [1024][128][64] fp16   @ byte offset 4*PO_OFF
// PL: [1024][128]     fp16   following
#define PO_OFF 5046272L

typedef short bvec8 __attribute__((ext_vector_type(8)));
typedef float fvec16 __attribute__((ext_vector_type(16)));
typedef _Float16 hvec4 __attribute__((ext_vector_type(4)));
typedef _Float16 hvec8 __attribute__((ext_vector_type(8)));

#if defined(__has_builtin)
#if __has_builtin(__builtin_amdgcn_cvt_pk_bf16_f32)
#define HAVE_CVTPK 1
#endif
#if __has_builtin(__builtin_amdgcn_permlane32_swap)
#define HAVE_PLSWAP 1
#endif
#endif

static __device__ __forceinline__ unsigned pk2(float a, float b) {
#ifdef HAVE_CVTPK
  auto r = __builtin_amdgcn_cvt_pk_bf16_f32(a, b);  // single v_cvt_pk_bf16_f32
  unsigned u; __builtin_memcpy(&u, &r, 4);
  return u;
#else
  unsigned ua = (__float_as_uint(a) + 0x8000u) >> 16;
  unsigned ub = (__float_as_uint(b) + 0x8000u) & 0xffff0000u;
  return ua | ub;
#endif
}
static __device__ __forceinline__ void async16(const short* g, short* l) {
  __builtin_amdgcn_global_load_lds((const __attribute__((address_space(1))) unsigned*)(void*)g,
                                   (__attribute__((address_space(3))) unsigned*)(void*)l, 16, 0, 0);
}

// ---------------- fused packs: K bf16 copy + V^T bf16 transpose ----------------
__global__ __launch_bounds__(256) void pack_all(const float* __restrict__ k,
                                                const float* __restrict__ v,
                                                short* __restrict__ W) {
  __shared__ float tl[64][65];
  int b = blockIdx.x, t = threadIdx.x;
  if (b < 896) {  // K pack: [h][7168][64], 16 contiguous elements/thread
    int h = b / 112, tile = b % 112, i0 = tile * 64;
    int r = t >> 2, c = t & 3;
    const float* src = k + ((long)(i0 + r) * 8 + h) * 64 + c * 16;
    short* dst = W + ((long)h * 7168 + i0 + r) * 64 + c * 16;
    union { unsigned u[8]; bvec8 v[2]; } tw;
#pragma unroll
    for (int q4 = 0; q4 < 4; q4++) {
      float4 x = *(const float4*)(src + q4 * 4);
      tw.u[q4 * 2 + 0] = pk2(x.x, x.y);
      tw.u[q4 * 2 + 1] = pk2(x.z, x.w);
    }
    *(bvec8*)dst = tw.v[0];
    *(bvec8*)(dst + 8) = tw.v[1];
  } else {        // V^T pack
    int b2 = b - 896;
    int h, tile, dil, L; long base;
    if (b2 < 896)       { L = 7168; dil = 1; h = b2 / 112; tile = b2 % 112; base = VB0; }
    else if (b2 < 1344) { int bb = b2 - 896;  L = 3584; dil = 2; h = bb / 56; tile = bb % 56; base = VB1; }
    else                { int bb = b2 - 1344; L = 1792; dil = 4; h = bb / 28; tile = bb % 28; base = VB2; }
    int i0 = tile * 64;
    int row = t >> 2, c = t & 3;
    const float* src = v + ((long)(i0 + row) * dil * 8 + h) * 64;
#pragma unroll
    for (int cc = 0; cc < 4; cc++) {
      int d0 = c * 16 + cc * 4;
      float4 x = *(const float4*)(src + d0);
      tl[row][d0 + 0] = x.x; tl[row][d0 + 1] = x.y;
      tl[row][d0 + 2] = x.z; tl[row][d0 + 3] = x.w;
    }
    __syncthreads();
    int d = t >> 2, part = t & 3;
    union { unsigned u[8]; bvec8 v[2]; } tw;
#pragma unroll
    for (int u2 = 0; u2 < 8; u2++)
      tw.u[u2] = pk2(tl[part * 16 + 2 * u2][d], tl[part * 16 + 2 * u2 + 1][d]);
    short* dst = W + base + ((long)h * 64 + d) * L + i0 + part * 16;
    *(bvec8*)dst = tw.v[0];
    *(bvec8*)(dst + 8) = tw.v[1];
  }
}

// cross-half P exchange
#ifdef HAVE_PLSWAP
#define PEXCH(fu, da0, da1, db0, db1)                                              \
  do {                                                                             \
    auto rr0 = __builtin_amdgcn_permlane32_swap((int)(da0), (int)(db0), false, false); \
    auto rr1 = __builtin_amdgcn_permlane32_swap((int)(da1), (int)(db1), false, false); \
    __builtin_memcpy(&fu.u4[0], &rr0, 4);                                          \
    __builtin_memcpy(&fu.u4[2], (const char*)&rr0 + 4, 4);                         \
    __builtin_memcpy(&fu.u4[1], &rr1, 4);                                          \
    __builtin_memcpy(&fu.u4[3], (const char*)&rr1 + 4, 4);                         \
  } while (0)
#else
#define PEXCH(fu, da0, da1, db0, db1)                                              \
  do {                                                                             \
    unsigned s0 = hb ? (da0) : (db0), s1 = hb ? (da1) : (db1);                     \
    unsigned x0 = __shfl_xor(s0, 32), x1 = __shfl_xor(s1, 32);                     \
    fu.u4[0] = hb ? x0 : (da0);  fu.u4[1] = hb ? x1 : (da1);                       \
    fu.u4[2] = hb ? (db0) : x0;  fu.u4[3] = hb ? (db1) : x1;                       \
  } while (0)
#endif

// one softmax slot from a single-key-half Sa: exp2 on 8 scores + l-accumulate +
// P pack/exchange + 2 PV MFMAs (V0 = d-half 0 fragment, V1 = d-half 1)
#define SOFTMAX_PV_H(SA, V0, V1, SP)                                               \
  do {                                                                             \
    const int r0_ = (SP) * 8;                                                      \
    float p[8];                                                                    \
    _Pragma("unroll") for (int u = 0; u < 8; u++)                                  \
        p[u] = __builtin_amdgcn_exp2f(SA[r0_ + u]);                                \
    lacc += ((p[0] + p[1]) + (p[2] + p[3])) + ((p[4] + p[5]) + (p[6] + p[7]));     \
    unsigned da0 = pk2(p[0], p[1]), da1 = pk2(p[2], p[3]);                         \
    unsigned db0 = pk2(p[4], p[5]), db1 = pk2(p[6], p[7]);                         \
    union { unsigned u4[4]; bvec8 v; } fu;                                         \
    PEXCH(fu, da0, da1, db0, db1);                                                 \
    __builtin_amdgcn_s_setprio(1);                                                 \
    Oa[0] = __builtin_amdgcn_mfma_f32_32x32x16_bf16((V0), fu.v, Oa[0], 0, 0, 0);   \
    Oa[1] = __builtin_amdgcn_mfma_f32_32x32x16_bf16((V1), fu.v, Oa[1], 0, 0, 0);   \
    __builtin_amdgcn_s_setprio(0);                                                 \
  } while (0)

// --------------------- main flash attention (S^T form) ---------------------
// R20 = R17 (grid 1280, seg2-first, fp16 partials, (256,4), LDS 2-buf sync)
// + R14's INTERLEAVED dual-Sa QK: both key-halves' QK chains are computed
// back-to-back (two independent 4-deep MFMA chains fill each other's dep
// latency), then per-half {vf -> softmax -> PV} (half1's exp2 issues under
// half0's PV tail; no barriers in between). Unlike R14, no kf/vf persistent
// register buffers (+48 regs) — peak live ~120 <= the (256,4) 128-reg cap.
// R19 post-mortem: direct global fragment loads are uncoalesced (stride
// 128-512B/lane -> 32 line-transactions per load); LDS staging stays.
__global__ __launch_bounds__(256, 4) void attn_kern(const float* __restrict__ q,
                                                    const short* __restrict__ W,
                                                    float* __restrict__ out,
                                                    _Float16* __restrict__ POh,
                                                    _Float16* __restrict__ PLh) {
  int b = blockIdx.x;
  int h, q0, dil, kt0, L, NT, pb; long vbo;
  if (b < 256) {        // seg2: long blocks first (28 tiles, direct out)
    h = b & 7; int qt = b >> 3;
    q0 = 3072 + qt * 128; dil = 4; L = 1792; vbo = VB2; kt0 = 0; NT = 28; pb = -1;
  } else if (b < 768) { // seg0: 8 splits x 14 tiles
    int i = b - 256; int sp = i & 7; h = (i >> 3) & 7; int qt = i >> 6;
    q0 = qt * 128; dil = 1; L = 7168; vbo = VB0; kt0 = sp * 14; NT = 14; pb = i;
  } else {              // seg1: 4 splits x 14 tiles
    int i = b - 768; int sp = i & 3; h = (i >> 2) & 7; int qt = i >> 5;
    q0 = 1024 + qt * 128; dil = 2; L = 3584; vbo = VB1; kt0 = sp * 14; NT = 14; pb = 512 + i;
  }
  const short* kb = W + (long)h * 7168 * 64;
  const short* vt = W + vbo + (long)h * 64 * L;
  const int dil64 = dil * 64;

  __shared__ __attribute__((aligned(16))) short sK[2][4096];  // XOR-swizzled
  __shared__ __attribute__((aligned(16))) short sV[2][4096];  // XOR-swizzled
  short* sKf = &sK[0][0];
  short* sVf = &sV[0][0];

  int t = threadIdx.x, lane = t & 63, w = t >> 6;
  int ln = lane & 31, hb = lane >> 5;

  // Q as B-operand (n = q-row = ln, k-els d = 16*ks + 8*hb + j), scale folds 1/8 * log2(e)
  bvec8 qb[4];
  {
    const float* qp = q + ((long)(q0 + w * 32 + ln) * 8 + h) * 64 + 8 * hb;
    const float qs = 0.125f * 1.44269504088896f;
#pragma unroll
    for (int ks = 0; ks < 4; ks++) {
      union { unsigned u[4]; bvec8 v; } qu;
#pragma unroll
      for (int jj = 0; jj < 4; jj++)
        qu.u[jj] = pk2(qs * qp[ks * 16 + 2 * jj], qs * qp[ks * 16 + 2 * jj + 1]);
      qb[ks] = qu.v;
    }
  }

  // staging: per-lane incrementing global pointers (strength-reduced)
  int srow = lane >> 3, sch = (lane & 7) ^ srow;
  const long kstep = 64L * dil64;
  const short* gk0; const short* gk1; const short* gv0; const short* gv1;
  {
    int row0 = (w * 2 + 0) * 8 + srow, row1 = (w * 2 + 1) * 8 + srow;
    long kb0 = (long)kt0 * 64;
    gk0 = kb + (kb0 + row0) * dil64 + sch * 8;
    gk1 = kb + (kb0 + row1) * dil64 + sch * 8;
    gv0 = vt + (long)row0 * L + kb0 + sch * 8;
    gv1 = vt + (long)row1 * L + kb0 + sch * 8;
  }
  const int ldoff = w * 2 * 512;
  auto stage = [&](int bo2) {
    async16(gk0, sKf + bo2 + ldoff);
    async16(gv0, sVf + bo2 + ldoff);
    async16(gk1, sKf + bo2 + ldoff + 512);
    async16(gv1, sVf + bo2 + ldoff + 512);
    gk0 += kstep; gk1 += kstep; gv0 += 64; gv1 += 64;
  };

  stage(0);  // tile 0 -> buf 0

  // LDS fragment offsets (XOR swizzle: stored col = chunk ^ (row&7))
  // koff[ks*2+mb]: K use -> mb = key-half row block, ks = d-chunk;
  //                V use -> mb = d-half row block,  ks = key-slot.
  int koff[8];
#pragma unroll
  for (int ks = 0; ks < 4; ks++)
#pragma unroll
    for (int mb = 0; mb < 2; mb++)
      koff[ks * 2 + mb] = (mb * 32 + ln) * 64 + (((2 * ks + hb) ^ (ln & 7)) * 8);

  fvec16 Oa[2];
  float lacc = 0.f;
#pragma unroll
  for (int i = 0; i < 16; i++) { Oa[0][i] = 0.f; Oa[1][i] = 0.f; }

  int bo = 0;
  for (int it = 0; it < NT; it++) {
    __syncthreads();                       // drains vmcnt -> tile it ready
    if (it < NT - 1) stage(bo ^ 4096);     // DMA overlaps full tile compute

    const short* sb = sKf + bo;
    const short* vb = sVf + bo;
    bo ^= 4096;

    // interleaved QK: two independent 4-deep chains fill each other's latency
    fvec16 Sa0, Sa1;
#pragma unroll
    for (int i = 0; i < 16; i++) { Sa0[i] = 0.f; Sa1[i] = 0.f; }
    __builtin_amdgcn_s_setprio(1);
#pragma unroll
    for (int ks = 0; ks < 4; ks++) {
      bvec8 kf0 = *(const bvec8*)(sb + koff[ks * 2 + 0]);
      bvec8 kf1 = *(const bvec8*)(sb + koff[ks * 2 + 1]);
      Sa0 = __builtin_amdgcn_mfma_f32_32x32x16_bf16(kf0, qb[ks], Sa0, 0, 0, 0);
      Sa1 = __builtin_amdgcn_mfma_f32_32x32x16_bf16(kf1, qb[ks], Sa1, 0, 0, 0);
    }
    __builtin_amdgcn_s_setprio(0);

    // half 0 (key slots 0,1): V frags then softmax+PV
    {
      bvec8 v00 = *(const bvec8*)(vb + koff[0 * 2 + 0]);
      bvec8 v01 = *(const bvec8*)(vb + koff[0 * 2 + 1]);
      bvec8 v10 = *(const bvec8*)(vb + koff[1 * 2 + 0]);
      bvec8 v11 = *(const bvec8*)(vb + koff[1 * 2 + 1]);
      SOFTMAX_PV_H(Sa0, v00, v01, 0);
      SOFTMAX_PV_H(Sa0, v10, v11, 1);
    }
    // half 1 (key slots 2,3)
    {
      bvec8 v00 = *(const bvec8*)(vb + koff[2 * 2 + 0]);
      bvec8 v01 = *(const bvec8*)(vb + koff[2 * 2 + 1]);
      bvec8 v10 = *(const bvec8*)(vb + koff[3 * 2 + 0]);
      bvec8 v11 = *(const bvec8*)(vb + koff[3 * 2 + 1]);
      SOFTMAX_PV_H(Sa1, v00, v01, 0);
      SOFTMAX_PV_H(Sa1, v10, v11, 1);
    }
  }

  // epilogue: O^T C-layout: qrow = ln, d = 32*mb2 + 8*r2 + 4*hb + r3
  float lf = lacc + __shfl_xor(lacc, 32);
  int wl = w * 32 + ln;
  if (pb >= 0) {
    _Float16* po = POh + ((long)pb * 128 + wl) * 64;
#pragma unroll
    for (int mb2 = 0; mb2 < 2; mb2++)
#pragma unroll
      for (int r2 = 0; r2 < 4; r2++) {
        hvec4 x = { (_Float16)Oa[mb2][r2 * 4 + 0], (_Float16)Oa[mb2][r2 * 4 + 1],
                    (_Float16)Oa[mb2][r2 * 4 + 2], (_Float16)Oa[mb2][r2 * 4 + 3] };
        *(hvec4*)(po + mb2 * 32 + r2 * 8 + hb * 4) = x;
      }
    if (hb == 0) PLh[(long)pb * 128 + wl] = (_Float16)lf;
  } else {
    float inv = 1.f / lf;
    float* op = out + ((long)(q0 + wl) * 8 + h) * 64;
#pragma unroll
    for (int mb2 = 0; mb2 < 2; mb2++)
#pragma unroll
      for (int r2 = 0; r2 < 4; r2++) {
        float4 x = { Oa[mb2][r2 * 4 + 0] * inv, Oa[mb2][r2 * 4 + 1] * inv,
                     Oa[mb2][r2 * 4 + 2] * inv, Oa[mb2][r2 * 4 + 3] * inv };
        *(float4*)(op + mb2 * 32 + r2 * 8 + hb * 4) = x;
      }
  }
}

// --------------- combine partials (seg0: 8 splits, seg1: 4 splits) ---------------
__global__ __launch_bounds__(256) void combine_kern(const _Float16* __restrict__ POh,
                                                    const _Float16* __restrict__ PLh,
                                                    float* __restrict__ out) {
  int g = blockIdx.x, t = threadIdx.x;
  int base, nsp, q0, h;
  if (g < 64) { int qt = g >> 3; h = g & 7; base = qt * 64 + h * 8; nsp = 8; q0 = qt * 128; }
  else { int gi = g - 64; int qt = gi >> 3; h = gi & 7; base = 512 + qt * 32 + h * 4; nsp = 4; q0 = 1024 + qt * 128; }
  int r = t >> 1, ch = (t & 1) * 32;
  float lt = 0.f;
  for (int sp = 0; sp < nsp; sp++) lt += (float)PLh[(long)(base + sp) * 128 + r];
  float inv = 1.f / lt;
  float acc[32];
#pragma unroll
  for (int j = 0; j < 32; j++) acc[j] = 0.f;
  for (int sp = 0; sp < nsp; sp++) {
    const hvec8* pb8 = (const hvec8*)(POh + ((long)(base + sp) * 128 + r) * 64 + ch);
#pragma unroll
    for (int j = 0; j < 4; j++) {
      hvec8 x = pb8[j];
#pragma unroll
      for (int kk = 0; kk < 8; kk++) acc[j * 8 + kk] += (float)x[kk];
    }
  }
  float4* op = (float4*)(out + ((long)(q0 + r) * 8 + h) * 64 + ch);
#pragma unroll
  for (int j = 0; j < 8; j++) {
    float4 x = { acc[j * 4 + 0] * inv, acc[j * 4 + 1] * inv,
                 acc[j * 4 + 2] * inv, acc[j * 4 + 3] * inv };
    op[j] = x;
  }
}

extern "C" void kernel_launch(void* const* d_in, const int* in_sizes, int n_in,
                              void* d_out, int out_size, void* d_ws, size_t ws_size,
                              hipStream_t stream) {
  const float* q = (const float*)d_in[0];
  const float* k = (const float*)d_in[1];
  const float* v = (const float*)d_in[2];
  float* out = (float*)d_out;
  short* W = (short*)d_ws;                 // bf16 packs (unchanged)
  _Float16* POh = (_Float16*)((float*)d_ws + PO_OFF);   // [1024][128][64] fp16
  _Float16* PLh = POh + 1024L * 128 * 64;               // [1024][128] fp16

  pack_all<<<2464, 256, 0, stream>>>(k, v, W);
  attn_kern<<<1280, 256, 0, stream>>>(q, W, out, POh, PLh);
  combine_kern<<<192, 256, 0, stream>>>(POh, PLh, out);
}